// Round 9
// baseline (68.394 us; speedup 1.0000x reference)
//
#include <hip/hip_runtime.h>
#include <math.h>

#define TABN 512
#define LE 4             // LUT entries per block
#define RPW 8            // rows per wave -> 8192 waves, 2048 blocks, 8 blocks/CU all resident
#define D 1000
#define DV4 250          // 1000 floats = 250 float4; row stride 4000B is 16B-aligned

// ---------------- LUT kernel: wide layout, 128 blocks x 256 threads (R6, proven) -------
__global__ __launch_bounds__(256) void lut_kernel(
    const float* __restrict__ w1, const float* __restrict__ b1,
    const float* __restrict__ w2, const float* __restrict__ b2,
    const float* __restrict__ w3, const float* __restrict__ b3,
    const float* __restrict__ w4, const float* __restrict__ b4,
    float* __restrict__ lut)
{
    __shared__ float h1s[LE][512];      // 8 KB
    __shared__ float pl2[LE][4][64];    // 4 KB
    __shared__ float h2s[LE][64];       // 1 KB
    const int t  = threadIdx.x;
    const int k  = t & 63;              // layer-2 output unit
    const int jc = t >> 6;              // j-chunk 0..3 (one per wave)
    const int e0 = blockIdx.x * LE;

    float s[LE];
#pragma unroll
    for (int e = 0; e < LE; ++e)
        s[e] = -1.0f + 2.0f * (float)(e0 + e) / (float)(TABN - 1);

    // layer 1: 1 -> 512
#pragma unroll
    for (int j = t; j < 512; j += 256) {
        float wj = w1[j], bj = b1[j];
#pragma unroll
        for (int e = 0; e < LE; ++e) {
            float v = fmaf(wj, s[e], bj);
            h1s[e][j] = v > 0.0f ? v : 0.0f;
        }
    }
    __syncthreads();

    // layer 2: 512 -> 64, j split 4 ways across waves
    float pacc[LE] = {0.f, 0.f, 0.f, 0.f};
    const int jbase = jc * 128;
#pragma unroll 4
    for (int jj = 0; jj < 128; ++jj) {
        int j = jbase + jj;
        float w = w2[j * 64 + k];
#pragma unroll
        for (int e = 0; e < LE; ++e)
            pacc[e] = fmaf(w, h1s[e][j], pacc[e]);
    }
#pragma unroll
    for (int e = 0; e < LE; ++e) pl2[e][jc][k] = pacc[e];
    __syncthreads();

    if (t < 64) {
#pragma unroll
        for (int e = 0; e < LE; ++e) {
            float a = b2[k] + ((pl2[e][0][k] + pl2[e][1][k]) +
                               (pl2[e][2][k] + pl2[e][3][k]));
            h2s[e][k] = a > 0.0f ? a : 0.0f;
        }
    }
    __syncthreads();

    // layer 3 (64->32) + layer 4 (32->1): threads 0..127, e = t>>5, m = t&31
    if (t < 32 * LE) {
        const int e = t >> 5, m = t & 31;
        float a = b3[m];
#pragma unroll 4
        for (int kk = 0; kk < 64; ++kk)
            a = fmaf(w3[kk * 32 + m], h2s[e][kk], a);
        float h3 = a > 0.0f ? a : 0.0f;
        float part = h3 * w4[m];
#pragma unroll
        for (int off = 16; off >= 1; off >>= 1)
            part += __shfl_xor(part, off, 32);
        if (m == 0)
            lut[e0 + e] = 1.0f / (1.0f + expf(-(part + b4[0])));
    }
}

// ---------------- main kernel: depth-1 pipeline at <=64 VGPR (q half in LDS) ----------
__device__ __forceinline__ float dot4(float4 a, float4 b, float acc) {
    acc = fmaf(a.x, b.x, acc);
    acc = fmaf(a.y, b.y, acc);
    acc = fmaf(a.z, b.z, acc);
    acc = fmaf(a.w, b.w, acc);
    return acc;
}

__global__ __launch_bounds__(256, 8) void sim_kernel(
    const float* __restrict__ query, const float* __restrict__ emb,
    const float* __restrict__ lut, float* __restrict__ out, int N)
{
    __shared__ float sLut[TABN];        // 2 KB
    __shared__ float4 qext[128];        // 2 KB: q[128..250) zero-padded; re-read per row
    const int t = threadIdx.x;
    const float4 zero4 = make_float4(0.f, 0.f, 0.f, 0.f);
    const float4* q4 = (const float4*)query;

    for (int i = t; i < TABN; i += 256) sLut[i] = lut[i];
    if (t < 128) qext[t] = (128 + t < DV4) ? q4[128 + t] : zero4;
    __syncthreads();

    const int lane = t & 63;
    const int wave = blockIdx.x * 4 + (t >> 6);
    const size_t base0 = (size_t)wave * RPW;
    if (base0 >= (size_t)N) return;

    // resident q fragments: only 8 VGPR
    float4 q0 = q4[lane];
    float4 q1 = q4[lane + 64];

    float nq = 0.f;
    {
        float4 qa = qext[lane];           // q[128+lane]
        float4 qb = qext[64 + lane];      // q[192+lane] (zero-padded)
        nq = dot4(q0, q0, nq); nq = dot4(q1, q1, nq);
        nq = dot4(qa, qa, nq); nq = dot4(qb, qb, nq);
    }
#pragma unroll
    for (int off = 32; off >= 1; off >>= 1) nq += __shfl_xor(nq, off, 64);
    const float qn = sqrtf(nq);

    // named buffers, pointer walked incrementally (no per-row mul)
    float4 A0, A1, A2, A3, B0, B1, B2, B3;
    const float4* pA = (const float4*)(emb + base0 * D);   // row base, walked by +DV4
    const float4* pB;

#define LOADROW(P0, P1, P2, P3, PTR)                                    \
    {                                                                   \
        P0 = PTR[lane];                                                 \
        P1 = PTR[lane + 64];                                            \
        P2 = PTR[lane + 128];                                           \
        P3 = (lane < DV4 - 192) ? PTR[lane + 192] : zero4;              \
    }

#define PROCROW(P0, P1, P2, P3, ROW)                                    \
    {                                                                   \
        float dt = 0.f, nn = 0.f;                                       \
        float4 qa = qext[lane];                                         \
        float4 qb = qext[64 + lane];                                    \
        dt = dot4(P0, q0, dt); nn = dot4(P0, P0, nn);                   \
        dt = dot4(P1, q1, dt); nn = dot4(P1, P1, nn);                   \
        dt = dot4(P2, qa, dt); nn = dot4(P2, P2, nn);                   \
        dt = dot4(P3, qb, dt); nn = dot4(P3, P3, nn);                   \
        _Pragma("unroll")                                               \
        for (int off = 32; off >= 1; off >>= 1) {                       \
            dt += __shfl_xor(dt, off, 64);                              \
            nn += __shfl_xor(nn, off, 64);                              \
        }                                                               \
        float sim = dt / fmaxf(sqrtf(nn) * qn, 1e-8f);                  \
        float tt = (sim + 1.0f) * (0.5f * (float)(TABN - 1));           \
        tt = fminf(fmaxf(tt, 0.0f), (float)(TABN - 1));                 \
        int i0 = (int)tt;                                               \
        if (i0 > TABN - 2) i0 = TABN - 2;                               \
        float fr = tt - (float)i0;                                      \
        float v0 = sLut[i0], v1 = sLut[i0 + 1];                         \
        if (lane == 0) out[ROW] = fmaf(v1 - v0, fr, v0);                \
    }

    LOADROW(A0, A1, A2, A3, pA);
#pragma unroll 1
    for (int r = 0; r < RPW; r += 2) {
        pB = pA + DV4;
        LOADROW(B0, B1, B2, B3, pB);              // in flight during A's reduce
        PROCROW(A0, A1, A2, A3, base0 + r);
        pA = pB + DV4;
        if (r + 2 < RPW) LOADROW(A0, A1, A2, A3, pA);
        PROCROW(B0, B1, B2, B3, base0 + r + 1);
    }
#undef LOADROW
#undef PROCROW
}

extern "C" void kernel_launch(void* const* d_in, const int* in_sizes, int n_in,
                              void* d_out, int out_size, void* d_ws, size_t ws_size,
                              hipStream_t stream) {
    const float* query = (const float*)d_in[0];
    const float* emb   = (const float*)d_in[1];
    const float* w1    = (const float*)d_in[2];
    const float* b1    = (const float*)d_in[3];
    const float* w2    = (const float*)d_in[4];
    const float* b2    = (const float*)d_in[5];
    const float* w3    = (const float*)d_in[6];
    const float* b3    = (const float*)d_in[7];
    const float* w4    = (const float*)d_in[8];
    const float* b4    = (const float*)d_in[9];
    float* lut = (float*)d_ws;
    float* out = (float*)d_out;
    const int N = in_sizes[1] / D;   // 65536

    lut_kernel<<<TABN / LE, 256, 0, stream>>>(w1, b1, w2, b2, w3, b3, w4, b4, lut);

    const int waves  = (N + RPW - 1) / RPW;      // 8192
    const int blocks = (waves + 3) / 4;          // 2048 = 8 blocks/CU, all resident at 64 VGPR
    sim_kernel<<<blocks, 256, 0, stream>>>(query, emb, lut, out, N);
}

// Round 11
// 58.200 us; speedup vs baseline: 1.1752x; 1.1752x over previous
//
#include <hip/hip_runtime.h>
#include <math.h>

#define TABN 512
#define LE 4             // LUT entries per block
#define RPW 8            // rows per wave
#define D 1000
#define DV4 250          // 1000 floats = 250 float4; row stride 4000B is 16B-aligned

typedef float v4f __attribute__((ext_vector_type(4)));   // clang vector: valid for nontemporal builtin

// ---------------- LUT kernel: wide layout, 128 blocks x 256 threads (R6, proven) -------
__global__ __launch_bounds__(256) void lut_kernel(
    const float* __restrict__ w1, const float* __restrict__ b1,
    const float* __restrict__ w2, const float* __restrict__ b2,
    const float* __restrict__ w3, const float* __restrict__ b3,
    const float* __restrict__ w4, const float* __restrict__ b4,
    float* __restrict__ lut)
{
    __shared__ float h1s[LE][512];      // 8 KB
    __shared__ float pl2[LE][4][64];    // 4 KB
    __shared__ float h2s[LE][64];       // 1 KB
    const int t  = threadIdx.x;
    const int k  = t & 63;              // layer-2 output unit
    const int jc = t >> 6;              // j-chunk 0..3 (one per wave)
    const int e0 = blockIdx.x * LE;

    float s[LE];
#pragma unroll
    for (int e = 0; e < LE; ++e)
        s[e] = -1.0f + 2.0f * (float)(e0 + e) / (float)(TABN - 1);

    // layer 1: 1 -> 512
#pragma unroll
    for (int j = t; j < 512; j += 256) {
        float wj = w1[j], bj = b1[j];
#pragma unroll
        for (int e = 0; e < LE; ++e) {
            float v = fmaf(wj, s[e], bj);
            h1s[e][j] = v > 0.0f ? v : 0.0f;
        }
    }
    __syncthreads();

    // layer 2: 512 -> 64, j split 4 ways across waves
    float pacc[LE] = {0.f, 0.f, 0.f, 0.f};
    const int jbase = jc * 128;
#pragma unroll 4
    for (int jj = 0; jj < 128; ++jj) {
        int j = jbase + jj;
        float w = w2[j * 64 + k];
#pragma unroll
        for (int e = 0; e < LE; ++e)
            pacc[e] = fmaf(w, h1s[e][j], pacc[e]);
    }
#pragma unroll
    for (int e = 0; e < LE; ++e) pl2[e][jc][k] = pacc[e];
    __syncthreads();

    if (t < 64) {
#pragma unroll
        for (int e = 0; e < LE; ++e) {
            float a = b2[k] + ((pl2[e][0][k] + pl2[e][1][k]) +
                               (pl2[e][2][k] + pl2[e][3][k]));
            h2s[e][k] = a > 0.0f ? a : 0.0f;
        }
    }
    __syncthreads();

    // layer 3 (64->32) + layer 4 (32->1): threads 0..127, e = t>>5, m = t&31
    if (t < 32 * LE) {
        const int e = t >> 5, m = t & 31;
        float a = b3[m];
#pragma unroll 4
        for (int kk = 0; kk < 64; ++kk)
            a = fmaf(w3[kk * 32 + m], h2s[e][kk], a);
        float h3 = a > 0.0f ? a : 0.0f;
        float part = h3 * w4[m];
#pragma unroll
        for (int off = 16; off >= 1; off >>= 1)
            part += __shfl_xor(part, off, 32);
        if (m == 0)
            lut[e0 + e] = 1.0f / (1.0f + expf(-(part + b4[0])));
    }
}

// ---------------- main kernel: R7 body + nontemporal emb loads ----------------
__device__ __forceinline__ float dot4v(v4f a, v4f b, float acc) {
    acc = fmaf(a.x, b.x, acc);
    acc = fmaf(a.y, b.y, acc);
    acc = fmaf(a.z, b.z, acc);
    acc = fmaf(a.w, b.w, acc);
    return acc;
}

__global__ __launch_bounds__(256) void sim_kernel(
    const float* __restrict__ query, const float* __restrict__ emb,
    const float* __restrict__ lut, float* __restrict__ out, int N)
{
    __shared__ float sLut[TABN];        // 2 KB: lut gathers become LDS reads
    const int t = threadIdx.x;
    for (int i = t; i < TABN; i += 256) sLut[i] = lut[i];
    __syncthreads();

    const int lane = t & 63;
    const int wave = blockIdx.x * 4 + (t >> 6);
    const size_t base0 = (size_t)wave * RPW;
    if (base0 >= (size_t)N) return;

    const v4f zero4 = (v4f){0.f, 0.f, 0.f, 0.f};
    const v4f* q4 = (const v4f*)query;
    v4f q0 = q4[lane];
    v4f q1 = q4[lane + 64];
    v4f q2 = q4[lane + 128];
    v4f q3 = (lane < DV4 - 192) ? q4[lane + 192] : zero4;

    float nq = 0.f;
    nq = dot4v(q0, q0, nq); nq = dot4v(q1, q1, nq);
    nq = dot4v(q2, q2, nq); nq = dot4v(q3, q3, nq);
#pragma unroll
    for (int off = 32; off >= 1; off >>= 1) nq += __shfl_xor(nq, off, 64);
    const float qn = sqrtf(nq);

    // named buffers (never arrays -> never scratch)
    v4f A0, A1, A2, A3, B0, B1, B2, B3;

    // emb is touch-once (262 MB > L3): nontemporal loads skip cache insertion,
    // keeping L1/L2 for q + lut and avoiding allocation overhead on the stream.
#define LOADROW(P0, P1, P2, P3, ROW)                                    \
    {                                                                   \
        const v4f* e4 = (const v4f*)(emb + (size_t)(ROW) * D);          \
        P0 = __builtin_nontemporal_load(e4 + lane);                     \
        P1 = __builtin_nontemporal_load(e4 + lane + 64);                \
        P2 = __builtin_nontemporal_load(e4 + lane + 128);               \
        P3 = (lane < DV4 - 192)                                         \
                 ? __builtin_nontemporal_load(e4 + lane + 192) : zero4; \
    }

#define PROCROW(P0, P1, P2, P3, ROW)                                    \
    {                                                                   \
        float dt = 0.f, nn = 0.f;                                       \
        dt = dot4v(P0, q0, dt); nn = dot4v(P0, P0, nn);                 \
        dt = dot4v(P1, q1, dt); nn = dot4v(P1, P1, nn);                 \
        dt = dot4v(P2, q2, dt); nn = dot4v(P2, P2, nn);                 \
        dt = dot4v(P3, q3, dt); nn = dot4v(P3, P3, nn);                 \
        _Pragma("unroll")                                               \
        for (int off = 32; off >= 1; off >>= 1) {                       \
            dt += __shfl_xor(dt, off, 64);                              \
            nn += __shfl_xor(nn, off, 64);                              \
        }                                                               \
        float sim = dt / fmaxf(sqrtf(nn) * qn, 1e-8f);                  \
        float tt = (sim + 1.0f) * (0.5f * (float)(TABN - 1));           \
        tt = fminf(fmaxf(tt, 0.0f), (float)(TABN - 1));                 \
        int i0 = (int)tt;                                               \
        if (i0 > TABN - 2) i0 = TABN - 2;                               \
        float fr = tt - (float)i0;                                      \
        float v0 = sLut[i0], v1 = sLut[i0 + 1];                         \
        if (lane == 0) out[ROW] = fmaf(v1 - v0, fr, v0);                \
    }

    LOADROW(A0, A1, A2, A3, base0);
#pragma unroll 1
    for (int r = 0; r < RPW; r += 2) {
        LOADROW(B0, B1, B2, B3, base0 + r + 1);   // in flight during A's reduce
        PROCROW(A0, A1, A2, A3, base0 + r);
        if (r + 2 < RPW) LOADROW(A0, A1, A2, A3, base0 + r + 2);
        PROCROW(B0, B1, B2, B3, base0 + r + 1);
    }
#undef LOADROW
#undef PROCROW
}

extern "C" void kernel_launch(void* const* d_in, const int* in_sizes, int n_in,
                              void* d_out, int out_size, void* d_ws, size_t ws_size,
                              hipStream_t stream) {
    const float* query = (const float*)d_in[0];
    const float* emb   = (const float*)d_in[1];
    const float* w1    = (const float*)d_in[2];
    const float* b1    = (const float*)d_in[3];
    const float* w2    = (const float*)d_in[4];
    const float* b2    = (const float*)d_in[5];
    const float* w3    = (const float*)d_in[6];
    const float* b3    = (const float*)d_in[7];
    const float* w4    = (const float*)d_in[8];
    const float* b4    = (const float*)d_in[9];
    float* lut = (float*)d_ws;
    float* out = (float*)d_out;
    const int N = in_sizes[1] / D;   // 65536

    lut_kernel<<<TABN / LE, 256, 0, stream>>>(w1, b1, w2, b2, w3, b3, w4, b4, lut);

    const int waves  = (N + RPW - 1) / RPW;      // 8192
    const int blocks = (waves + 3) / 4;          // 2048
    sim_kernel<<<blocks, 256, 0, stream>>>(query, emb, lut, out, N);
}

// Round 12
// 56.575 us; speedup vs baseline: 1.2089x; 1.0287x over previous
//
#include <hip/hip_runtime.h>
#include <math.h>

#define TABN 512
#define LE 4             // LUT entries per block
#define RPW 8            // rows per wave
#define D 1000
#define DV4 250          // 1000 floats = 250 float4; row stride 4000B is 16B-aligned

typedef float v4f __attribute__((ext_vector_type(4)));   // clang vector: valid for nontemporal builtin

// ---------------- LUT kernel: wide layout, 128 blocks x 256 threads (R6, proven) -------
__global__ __launch_bounds__(256) void lut_kernel(
    const float* __restrict__ w1, const float* __restrict__ b1,
    const float* __restrict__ w2, const float* __restrict__ b2,
    const float* __restrict__ w3, const float* __restrict__ b3,
    const float* __restrict__ w4, const float* __restrict__ b4,
    float* __restrict__ lut)
{
    __shared__ float h1s[LE][512];      // 8 KB
    __shared__ float pl2[LE][4][64];    // 4 KB
    __shared__ float h2s[LE][64];       // 1 KB
    const int t  = threadIdx.x;
    const int k  = t & 63;              // layer-2 output unit
    const int jc = t >> 6;              // j-chunk 0..3 (one per wave)
    const int e0 = blockIdx.x * LE;

    float s[LE];
#pragma unroll
    for (int e = 0; e < LE; ++e)
        s[e] = -1.0f + 2.0f * (float)(e0 + e) / (float)(TABN - 1);

    // layer 1: 1 -> 512
#pragma unroll
    for (int j = t; j < 512; j += 256) {
        float wj = w1[j], bj = b1[j];
#pragma unroll
        for (int e = 0; e < LE; ++e) {
            float v = fmaf(wj, s[e], bj);
            h1s[e][j] = v > 0.0f ? v : 0.0f;
        }
    }
    __syncthreads();

    // layer 2: 512 -> 64, j split 4 ways across waves
    float pacc[LE] = {0.f, 0.f, 0.f, 0.f};
    const int jbase = jc * 128;
#pragma unroll 4
    for (int jj = 0; jj < 128; ++jj) {
        int j = jbase + jj;
        float w = w2[j * 64 + k];
#pragma unroll
        for (int e = 0; e < LE; ++e)
            pacc[e] = fmaf(w, h1s[e][j], pacc[e]);
    }
#pragma unroll
    for (int e = 0; e < LE; ++e) pl2[e][jc][k] = pacc[e];
    __syncthreads();

    if (t < 64) {
#pragma unroll
        for (int e = 0; e < LE; ++e) {
            float a = b2[k] + ((pl2[e][0][k] + pl2[e][1][k]) +
                               (pl2[e][2][k] + pl2[e][3][k]));
            h2s[e][k] = a > 0.0f ? a : 0.0f;
        }
    }
    __syncthreads();

    // layer 3 (64->32) + layer 4 (32->1): threads 0..127, e = t>>5, m = t&31
    if (t < 32 * LE) {
        const int e = t >> 5, m = t & 31;
        float a = b3[m];
#pragma unroll 4
        for (int kk = 0; kk < 64; ++kk)
            a = fmaf(w3[kk * 32 + m], h2s[e][kk], a);
        float h3 = a > 0.0f ? a : 0.0f;
        float part = h3 * w4[m];
#pragma unroll
        for (int off = 16; off >= 1; off >>= 1)
            part += __shfl_xor(part, off, 32);
        if (m == 0)
            lut[e0 + e] = 1.0f / (1.0f + expf(-(part + b4[0])));
    }
}

// ---------------- main kernel: R11 body + DPP row-of-16 reduce ----------------
__device__ __forceinline__ float dot4v(v4f a, v4f b, float acc) {
    acc = fmaf(a.x, b.x, acc);
    acc = fmaf(a.y, b.y, acc);
    acc = fmaf(a.z, b.z, acc);
    acc = fmaf(a.w, b.w, acc);
    return acc;
}

// sum across each row of 16 lanes at VALU speed (no LDS unit):
// xor1 = quad_perm(1,0,3,2)=0xB1, xor2 = quad_perm(2,3,0,1)=0x4E,
// then row_ror:4 (0x124) and row_ror:8 (0x128) accumulate the 4 quad-sums.
__device__ __forceinline__ float dpp_rowsum16(float v) {
    int x;
    x = __builtin_amdgcn_update_dpp(0, __float_as_int(v), 0xB1, 0xF, 0xF, true);
    v += __int_as_float(x);
    x = __builtin_amdgcn_update_dpp(0, __float_as_int(v), 0x4E, 0xF, 0xF, true);
    v += __int_as_float(x);
    x = __builtin_amdgcn_update_dpp(0, __float_as_int(v), 0x124, 0xF, 0xF, true);
    v += __int_as_float(x);
    x = __builtin_amdgcn_update_dpp(0, __float_as_int(v), 0x128, 0xF, 0xF, true);
    v += __int_as_float(x);
    return v;
}

__global__ __launch_bounds__(256) void sim_kernel(
    const float* __restrict__ query, const float* __restrict__ emb,
    const float* __restrict__ lut, float* __restrict__ out, int N)
{
    __shared__ float sLut[TABN];        // 2 KB: lut gathers become LDS reads
    const int t = threadIdx.x;
    for (int i = t; i < TABN; i += 256) sLut[i] = lut[i];
    __syncthreads();

    const int lane = t & 63;
    const int wave = blockIdx.x * 4 + (t >> 6);
    const size_t base0 = (size_t)wave * RPW;
    if (base0 >= (size_t)N) return;

    const v4f zero4 = (v4f){0.f, 0.f, 0.f, 0.f};
    const v4f* q4 = (const v4f*)query;
    v4f q0 = q4[lane];
    v4f q1 = q4[lane + 64];
    v4f q2 = q4[lane + 128];
    v4f q3 = (lane < DV4 - 192) ? q4[lane + 192] : zero4;

    float nq = 0.f;
    nq = dot4v(q0, q0, nq); nq = dot4v(q1, q1, nq);
    nq = dot4v(q2, q2, nq); nq = dot4v(q3, q3, nq);
    nq = dpp_rowsum16(nq);
    nq += __shfl_xor(nq, 16, 64);
    nq += __shfl_xor(nq, 32, 64);
    const float qn = sqrtf(nq);

    // named buffers (never arrays -> never scratch)
    v4f A0, A1, A2, A3, B0, B1, B2, B3;

    // emb is touch-once (262 MB > L3): nontemporal loads skip cache insertion.
#define LOADROW(P0, P1, P2, P3, ROW)                                    \
    {                                                                   \
        const v4f* e4 = (const v4f*)(emb + (size_t)(ROW) * D);          \
        P0 = __builtin_nontemporal_load(e4 + lane);                     \
        P1 = __builtin_nontemporal_load(e4 + lane + 64);                \
        P2 = __builtin_nontemporal_load(e4 + lane + 128);               \
        P3 = (lane < DV4 - 192)                                         \
                 ? __builtin_nontemporal_load(e4 + lane + 192) : zero4; \
    }

#define PROCROW(P0, P1, P2, P3, ROW)                                    \
    {                                                                   \
        float dt = 0.f, nn = 0.f;                                       \
        dt = dot4v(P0, q0, dt); nn = dot4v(P0, P0, nn);                 \
        dt = dot4v(P1, q1, dt); nn = dot4v(P1, P1, nn);                 \
        dt = dot4v(P2, q2, dt); nn = dot4v(P2, P2, nn);                 \
        dt = dot4v(P3, q3, dt); nn = dot4v(P3, P3, nn);                 \
        dt = dpp_rowsum16(dt);                                          \
        nn = dpp_rowsum16(nn);                                          \
        dt += __shfl_xor(dt, 16, 64);  nn += __shfl_xor(nn, 16, 64);    \
        dt += __shfl_xor(dt, 32, 64);  nn += __shfl_xor(nn, 32, 64);    \
        float sim = dt / fmaxf(sqrtf(nn) * qn, 1e-8f);                  \
        float tt = (sim + 1.0f) * (0.5f * (float)(TABN - 1));           \
        tt = fminf(fmaxf(tt, 0.0f), (float)(TABN - 1));                 \
        int i0 = (int)tt;                                               \
        if (i0 > TABN - 2) i0 = TABN - 2;                               \
        float fr = tt - (float)i0;                                      \
        float v0 = sLut[i0], v1 = sLut[i0 + 1];                         \
        if (lane == 0) out[ROW] = fmaf(v1 - v0, fr, v0);                \
    }

    LOADROW(A0, A1, A2, A3, base0);
#pragma unroll 1
    for (int r = 0; r < RPW; r += 2) {
        LOADROW(B0, B1, B2, B3, base0 + r + 1);   // in flight during A's reduce
        PROCROW(A0, A1, A2, A3, base0 + r);
        if (r + 2 < RPW) LOADROW(A0, A1, A2, A3, base0 + r + 2);
        PROCROW(B0, B1, B2, B3, base0 + r + 1);
    }
#undef LOADROW
#undef PROCROW
}

extern "C" void kernel_launch(void* const* d_in, const int* in_sizes, int n_in,
                              void* d_out, int out_size, void* d_ws, size_t ws_size,
                              hipStream_t stream) {
    const float* query = (const float*)d_in[0];
    const float* emb   = (const float*)d_in[1];
    const float* w1    = (const float*)d_in[2];
    const float* b1    = (const float*)d_in[3];
    const float* w2    = (const float*)d_in[4];
    const float* b2    = (const float*)d_in[5];
    const float* w3    = (const float*)d_in[6];
    const float* b3    = (const float*)d_in[7];
    const float* w4    = (const float*)d_in[8];
    const float* b4    = (const float*)d_in[9];
    float* lut = (float*)d_ws;
    float* out = (float*)d_out;
    const int N = in_sizes[1] / D;   // 65536

    lut_kernel<<<TABN / LE, 256, 0, stream>>>(w1, b1, w2, b2, w3, b3, w4, b4, lut);

    const int waves  = (N + RPW - 1) / RPW;      // 8192
    const int blocks = (waves + 3) / 4;          // 2048
    sim_kernel<<<blocks, 256, 0, stream>>>(query, emb, lut, out, N);
}

// Round 13
// 55.937 us; speedup vs baseline: 1.2227x; 1.0114x over previous
//
#include <hip/hip_runtime.h>
#include <math.h>

#define TABN 512
#define LE 4             // LUT entries per block
#define RPW 8            // rows per wave
#define D 1000
#define DV4 250          // 1000 floats = 250 float4; row stride 4000B is 16B-aligned

typedef float v4f __attribute__((ext_vector_type(4)));   // clang vector: valid for nontemporal builtin

// ---------------- LUT kernel: wide layout, 128 blocks x 256 threads (R6, proven) -------
__global__ __launch_bounds__(256) void lut_kernel(
    const float* __restrict__ w1, const float* __restrict__ b1,
    const float* __restrict__ w2, const float* __restrict__ b2,
    const float* __restrict__ w3, const float* __restrict__ b3,
    const float* __restrict__ w4, const float* __restrict__ b4,
    float* __restrict__ lut)
{
    __shared__ float h1s[LE][512];      // 8 KB
    __shared__ float pl2[LE][4][64];    // 4 KB
    __shared__ float h2s[LE][64];       // 1 KB
    const int t  = threadIdx.x;
    const int k  = t & 63;              // layer-2 output unit
    const int jc = t >> 6;              // j-chunk 0..3 (one per wave)
    const int e0 = blockIdx.x * LE;

    float s[LE];
#pragma unroll
    for (int e = 0; e < LE; ++e)
        s[e] = -1.0f + 2.0f * (float)(e0 + e) / (float)(TABN - 1);

    // layer 1: 1 -> 512
#pragma unroll
    for (int j = t; j < 512; j += 256) {
        float wj = w1[j], bj = b1[j];
#pragma unroll
        for (int e = 0; e < LE; ++e) {
            float v = fmaf(wj, s[e], bj);
            h1s[e][j] = v > 0.0f ? v : 0.0f;
        }
    }
    __syncthreads();

    // layer 2: 512 -> 64, j split 4 ways across waves
    float pacc[LE] = {0.f, 0.f, 0.f, 0.f};
    const int jbase = jc * 128;
#pragma unroll 4
    for (int jj = 0; jj < 128; ++jj) {
        int j = jbase + jj;
        float w = w2[j * 64 + k];
#pragma unroll
        for (int e = 0; e < LE; ++e)
            pacc[e] = fmaf(w, h1s[e][j], pacc[e]);
    }
#pragma unroll
    for (int e = 0; e < LE; ++e) pl2[e][jc][k] = pacc[e];
    __syncthreads();

    if (t < 64) {
#pragma unroll
        for (int e = 0; e < LE; ++e) {
            float a = b2[k] + ((pl2[e][0][k] + pl2[e][1][k]) +
                               (pl2[e][2][k] + pl2[e][3][k]));
            h2s[e][k] = a > 0.0f ? a : 0.0f;
        }
    }
    __syncthreads();

    // layer 3 (64->32) + layer 4 (32->1): threads 0..127, e = t>>5, m = t&31
    if (t < 32 * LE) {
        const int e = t >> 5, m = t & 31;
        float a = b3[m];
#pragma unroll 4
        for (int kk = 0; kk < 64; ++kk)
            a = fmaf(w3[kk * 32 + m], h2s[e][kk], a);
        float h3 = a > 0.0f ? a : 0.0f;
        float part = h3 * w4[m];
#pragma unroll
        for (int off = 16; off >= 1; off >>= 1)
            part += __shfl_xor(part, off, 32);
        if (m == 0)
            lut[e0 + e] = 1.0f / (1.0f + expf(-(part + b4[0])));
    }
}

// ---------------- main kernel: full-DPP 64-lane reduce (zero LDS-unit ops) ----------
__device__ __forceinline__ float dot4v(v4f a, v4f b, float acc) {
    acc = fmaf(a.x, b.x, acc);
    acc = fmaf(a.y, b.y, acc);
    acc = fmaf(a.z, b.z, acc);
    acc = fmaf(a.w, b.w, acc);
    return acc;
}

// Full 64-lane sum entirely on the VALU pipe.
// quad_perm xor1 (0xB1), xor2 (0x4E), row_ror:4 (0x124), row_ror:8 (0x128):
// every lane holds its row-of-16 total. Then row_bcast15 (0x142, rows 1&3)
// and row_bcast31 (0x143, row 3): lanes 48..63 hold the full wave sum.
__device__ __forceinline__ float dpp_wavesum64(float v) {
    int x;
    x = __builtin_amdgcn_update_dpp(0, __float_as_int(v), 0xB1,  0xF, 0xF, true);
    v += __int_as_float(x);
    x = __builtin_amdgcn_update_dpp(0, __float_as_int(v), 0x4E,  0xF, 0xF, true);
    v += __int_as_float(x);
    x = __builtin_amdgcn_update_dpp(0, __float_as_int(v), 0x124, 0xF, 0xF, true);
    v += __int_as_float(x);
    x = __builtin_amdgcn_update_dpp(0, __float_as_int(v), 0x128, 0xF, 0xF, true);
    v += __int_as_float(x);
    x = __builtin_amdgcn_update_dpp(0, __float_as_int(v), 0x142, 0xA, 0xF, true);
    v += __int_as_float(x);   // row1 += row0 total; row3 += row2 total
    x = __builtin_amdgcn_update_dpp(0, __float_as_int(v), 0x143, 0x8, 0xF, true);
    v += __int_as_float(x);   // row3 += (rows0+1 total from lane 31)
    return v;                 // valid in lanes 48..63
}

__global__ __launch_bounds__(256) void sim_kernel(
    const float* __restrict__ query, const float* __restrict__ emb,
    const float* __restrict__ lut, float* __restrict__ out, int N)
{
    __shared__ float sLut[TABN];        // 2 KB: lut gathers become LDS reads
    const int t = threadIdx.x;
    for (int i = t; i < TABN; i += 256) sLut[i] = lut[i];
    __syncthreads();

    const int lane = t & 63;
    const int wave = blockIdx.x * 4 + (t >> 6);
    const size_t base0 = (size_t)wave * RPW;
    if (base0 >= (size_t)N) return;

    const v4f zero4 = (v4f){0.f, 0.f, 0.f, 0.f};
    const v4f* q4 = (const v4f*)query;
    v4f q0 = q4[lane];
    v4f q1 = q4[lane + 64];
    v4f q2 = q4[lane + 128];
    v4f q3 = (lane < DV4 - 192) ? q4[lane + 192] : zero4;

    float nq = 0.f;
    nq = dot4v(q0, q0, nq); nq = dot4v(q1, q1, nq);
    nq = dot4v(q2, q2, nq); nq = dot4v(q3, q3, nq);
    nq = dpp_wavesum64(nq);
    nq = __shfl(nq, 63, 64);            // broadcast once per wave (not per row)
    const float qn = sqrtf(nq);

    // named buffers (never arrays -> never scratch)
    v4f A0, A1, A2, A3, B0, B1, B2, B3;

    // emb is touch-once (262 MB > L3): nontemporal loads skip cache insertion.
#define LOADROW(P0, P1, P2, P3, ROW)                                    \
    {                                                                   \
        const v4f* e4 = (const v4f*)(emb + (size_t)(ROW) * D);          \
        P0 = __builtin_nontemporal_load(e4 + lane);                     \
        P1 = __builtin_nontemporal_load(e4 + lane + 64);                \
        P2 = __builtin_nontemporal_load(e4 + lane + 128);               \
        P3 = (lane < DV4 - 192)                                         \
                 ? __builtin_nontemporal_load(e4 + lane + 192) : zero4; \
    }

#define PROCROW(P0, P1, P2, P3, ROW)                                    \
    {                                                                   \
        float dt = 0.f, nn = 0.f;                                       \
        dt = dot4v(P0, q0, dt); nn = dot4v(P0, P0, nn);                 \
        dt = dot4v(P1, q1, dt); nn = dot4v(P1, P1, nn);                 \
        dt = dot4v(P2, q2, dt); nn = dot4v(P2, P2, nn);                 \
        dt = dot4v(P3, q3, dt); nn = dot4v(P3, P3, nn);                 \
        dt = dpp_wavesum64(dt);                                         \
        nn = dpp_wavesum64(nn);                                         \
        float sim = dt / fmaxf(sqrtf(nn) * qn, 1e-8f);                  \
        float tt = (sim + 1.0f) * (0.5f * (float)(TABN - 1));           \
        tt = fminf(fmaxf(tt, 0.0f), (float)(TABN - 1));                 \
        int i0 = (int)tt;                                               \
        if (i0 > TABN - 2) i0 = TABN - 2;                               \
        float fr = tt - (float)i0;                                      \
        float v0 = sLut[i0], v1 = sLut[i0 + 1];                         \
        if (lane == 63) out[ROW] = fmaf(v1 - v0, fr, v0);               \
    }

    LOADROW(A0, A1, A2, A3, base0);
#pragma unroll 1
    for (int r = 0; r < RPW; r += 2) {
        LOADROW(B0, B1, B2, B3, base0 + r + 1);   // in flight during A's reduce
        PROCROW(A0, A1, A2, A3, base0 + r);
        if (r + 2 < RPW) LOADROW(A0, A1, A2, A3, base0 + r + 2);
        PROCROW(B0, B1, B2, B3, base0 + r + 1);
    }
#undef LOADROW
#undef PROCROW
}

extern "C" void kernel_launch(void* const* d_in, const int* in_sizes, int n_in,
                              void* d_out, int out_size, void* d_ws, size_t ws_size,
                              hipStream_t stream) {
    const float* query = (const float*)d_in[0];
    const float* emb   = (const float*)d_in[1];
    const float* w1    = (const float*)d_in[2];
    const float* b1    = (const float*)d_in[3];
    const float* w2    = (const float*)d_in[4];
    const float* b2    = (const float*)d_in[5];
    const float* w3    = (const float*)d_in[6];
    const float* b3    = (const float*)d_in[7];
    const float* w4    = (const float*)d_in[8];
    const float* b4    = (const float*)d_in[9];
    float* lut = (float*)d_ws;
    float* out = (float*)d_out;
    const int N = in_sizes[1] / D;   // 65536

    lut_kernel<<<TABN / LE, 256, 0, stream>>>(w1, b1, w2, b2, w3, b3, w4, b4, lut);

    const int waves  = (N + RPW - 1) / RPW;      // 8192
    const int blocks = (waves + 3) / 4;          // 2048
    sim_kernel<<<blocks, 256, 0, stream>>>(query, emb, lut, out, N);
}